// Round 7
// baseline (635.254 us; speedup 1.0000x reference)
//
#include <hip/hip_runtime.h>
#include <stdint.h>

// GIN GNN: N=40000, E=640000, H=128, 5 layers, PROJ=256.
// R15 = R13 resubmitted a second time (R13/R14 rounds were both broker-side
// container failures with no kernel signal; source is unchanged from the
// R12-derived split). Structure: aggregate_k (10000 blocks, full gather
// concurrency) writes zin hi/lo bf16 pairs ONTO raw; gemm1_k (625 blocks)
// stages 64 rows to LDS, hi/lo GEMM1, writes z1 bf16 to the SAME bytes +
// BN1 stats; mlp2_k reads z1, BN1+relu at staging, GEMM2, writes z2 fp32 to
// the same bytes + BN2 stats. zin/z1/z2 time-share one buffer ->
// footprint 39.7MB (< R9's proven 50MB). Numerics bit-identical to R12
// (passed, absmax 0.1054).

typedef unsigned short ushort_t;
typedef unsigned int uint_t;
typedef __attribute__((ext_vector_type(8))) short bf16x8;
typedef __attribute__((ext_vector_type(16))) float f32x16;

#define MFMA32(a, b, c) __builtin_amdgcn_mfma_f32_32x32x16_bf16(a, b, c, 0, 0, 0)

__device__ inline ushort_t f2bf(float f) {
  uint_t u = __builtin_bit_cast(uint_t, f);
  u += 0x7FFFu + ((u >> 16) & 1u);
  return (ushort_t)(u >> 16);
}
__device__ inline float bf2f(uint_t h) {  // low 16 bits
  uint_t u = (h & 0xFFFFu) << 16;
  return __builtin_bit_cast(float, u);
}
__device__ inline uint_t pack2(float a, float b) {
  return (uint_t)f2bf(a) | ((uint_t)f2bf(b) << 16);
}
__device__ inline f32x16 zero16() {
  f32x16 z;
#pragma unroll
  for (int i = 0; i < 16; ++i) z[i] = 0.f;
  return z;
}

// ---------- precompute ----------

// comb[l][c][128] bf16, c = a0|a1<<4|a2<<8
__global__ __launch_bounds__(256) void bond_comb_k(
    const float* __restrict__ bemb, ushort_t* __restrict__ comb)
{
  int idx = blockIdx.x * 256 + threadIdx.x;  // over 5*4096*64
  if (idx >= 5 * 4096 * 64) return;
  int lane = idx & 63, c = (idx >> 6) & 4095, l = idx >> 18;
  const float2* b2 = (const float2*)(bemb + (size_t)l * 3 * 16 * 128);
  float2 e0 = b2[(c & 15) * 64 + lane];
  float2 e1 = b2[(16 + ((c >> 4) & 15)) * 64 + lane];
  float2 e2 = b2[(32 + (c >> 8)) * 64 + lane];
  ((uint_t*)comb)[idx] = pack2(e0.x + e1.x + e2.x, e0.y + e1.y + e2.y);
}

// All 11 weight swizzles in one launch. m<6: K=128,N=256 (w1 x5, linw);
// m>=6: K=256,N=128 (w2 x5).
__global__ __launch_bounds__(256) void swz_all_k(
    const float* __restrict__ w1, const float* __restrict__ linw,
    const float* __restrict__ w2, ushort_t* __restrict__ bswz1,
    ushort_t* __restrict__ bswz2)
{
  int t = blockIdx.x * 256 + threadIdx.x;  // 11*4096
  if (t >= 11 * 4096) return;
  int m = t >> 12, tt = t & 4095, lane = tt & 63;
  if (m < 6) {
    const float* w = (m < 5) ? (w1 + (size_t)m * 32768) : linw;
    ushort_t* o = bswz1 + (size_t)m * 32768;
    int nt = (tt >> 6) & 7, s = tt >> 9;
    int kb = s * 16 + (lane >> 5) * 8, n = nt * 32 + (lane & 31);
    ushort_t tmp[8];
#pragma unroll
    for (int j = 0; j < 8; ++j) tmp[j] = f2bf(w[(size_t)(kb + j) * 256 + n]);
    ((uint4*)o)[tt] = *(uint4*)tmp;
  } else {
    int mm = m - 6;
    const float* w = w2 + (size_t)mm * 32768;
    ushort_t* o = bswz2 + (size_t)mm * 32768;
    int nt = (tt >> 6) & 3, s = tt >> 8;
    int kb = s * 16 + (lane >> 5) * 8, n = nt * 32 + (lane & 31);
    ushort_t tmp[8];
#pragma unroll
    for (int j = 0; j < 8; ++j) tmp[j] = f2bf(w[(size_t)(kb + j) * 128 + n]);
    ((uint4*)o)[tt] = *(uint4*)tmp;
  }
}

// ---------- graph preprocessing ----------

__global__ void zero_int_k(int* p, int n) {
  int i = blockIdx.x * 256 + threadIdx.x;
  if (i < n) p[i] = 0;
}

__global__ void hist_k(const int* __restrict__ ei, int* __restrict__ cnt, int E) {
  int e = blockIdx.x * 256 + threadIdx.x;
  if (e >= E) return;
  atomicAdd(&cnt[ei[E + e]], 1);
}

__global__ __launch_bounds__(256) void block_sum_k(
    const int* __restrict__ cnt, int* __restrict__ bsum, int N)
{
  __shared__ int red[256];
  int t = threadIdx.x, idx = blockIdx.x * 256 + t;
  red[t] = (idx < N) ? cnt[idx] : 0;
  __syncthreads();
  for (int o = 128; o > 0; o >>= 1) {
    if (t < o) red[t] += red[t + o];
    __syncthreads();
  }
  if (t == 0) bsum[blockIdx.x] = red[0];
}

__global__ __launch_bounds__(256) void scan_bsum_k(
    int* __restrict__ bsum, int* __restrict__ rsN, int nb)
{
  __shared__ int s[256];
  int t = threadIdx.x;
  s[t] = (t < nb) ? bsum[t] : 0;
  __syncthreads();
  for (int o = 1; o < 256; o <<= 1) {
    int v = (t >= o) ? s[t - o] : 0;
    __syncthreads();
    s[t] += v;
    __syncthreads();
  }
  if (t < nb) bsum[t] = (t == 0) ? 0 : s[t - 1];
  if (t == nb - 1) *rsN = s[t];
}

__global__ __launch_bounds__(256) void scan_write_k(
    const int* __restrict__ cnt, const int* __restrict__ bsum,
    int* __restrict__ rs, int* __restrict__ cursor, int N)
{
  __shared__ int s[256];
  int t = threadIdx.x, idx = blockIdx.x * 256 + t;
  int v = (idx < N) ? cnt[idx] : 0;
  s[t] = v;
  __syncthreads();
  for (int o = 1; o < 256; o <<= 1) {
    int u = (t >= o) ? s[t - o] : 0;
    __syncthreads();
    s[t] += u;
    __syncthreads();
  }
  int excl = s[t] - v + bsum[blockIdx.x];
  if (idx < N) { rs[idx] = excl; cursor[idx] = excl; }
}

__global__ void scatter_k(const int* __restrict__ ei, const int* __restrict__ ea,
                          int* __restrict__ cursor, uint32_t* __restrict__ sorted, int E)
{
  int e = blockIdx.x * 256 + threadIdx.x;
  if (e >= E) return;
  int src = ei[e], dst = ei[E + e];
  int a0 = ea[e * 3], a1 = ea[e * 3 + 1], a2 = ea[e * 3 + 2];
  int pos = atomicAdd(&cursor[dst], 1);
  sorted[pos] = (uint32_t)src | ((uint32_t)a0 << 16) | ((uint32_t)a1 << 20) | ((uint32_t)a2 << 24);
}

// ---------- node pipeline ----------

// Layer-0 h (no BN): write bf16 directly into hbn. Block 0 zeroes BN1 stats
// for layer 0's gemm1_k.
__global__ __launch_bounds__(256) void atom_encode_k(
    const int* __restrict__ x, const float* __restrict__ aemb,
    ushort_t* __restrict__ hbn, float* __restrict__ stats, int N)
{
  if (blockIdx.x == 0) {
    stats[threadIdx.x] = 0.f;
    stats[threadIdx.x + 256] = 0.f;
  }
  int idx = blockIdx.x * 256 + threadIdx.x;
  if (idx >= N * 64) return;
  int n = idx >> 6, lane = idx & 63;
  const int* xr = x + n * 9;
  float sx = 0.f, sy = 0.f;
#pragma unroll
  for (int f = 0; f < 9; ++f) {
    float2 e = ((const float2*)(aemb + (size_t)(f * 128 + xr[f]) * 128))[lane];
    sx += e.x; sy += e.y;
  }
  ((uint_t*)hbn)[idx] = pack2(sx, sy);
}

// Materialize hbn = relu(BN(raw fp32)) as bf16, once per layer (layers 1..4).
// Block 0 zeroes BN1 stats (statsZero[0..511]) for the upcoming gemm1_k.
__global__ __launch_bounds__(256) void bnrelu_k(
    const float* __restrict__ raw, const float* __restrict__ stats2,
    const float* __restrict__ g, const float* __restrict__ bb,
    ushort_t* __restrict__ hbn, float* __restrict__ statsZero,
    float invN, int total)
{
  if (blockIdx.x == 0) {
    statsZero[threadIdx.x] = 0.f;
    statsZero[threadIdx.x + 256] = 0.f;
  }
  int t = blockIdx.x * 256 + threadIdx.x;
  int lane = t & 63;
  int c0 = 2 * lane, c1 = c0 + 1;
  float mu0 = stats2[c0] * invN, mu1 = stats2[c1] * invN;
  float v0 = stats2[128 + c0] * invN - mu0 * mu0;
  float v1 = stats2[128 + c1] * invN - mu1 * mu1;
  float scx = rsqrtf(v0 + 1e-5f) * g[c0];
  float scy = rsqrtf(v1 + 1e-5f) * g[c1];
  float shx = bb[c0] - mu0 * scx;
  float shy = bb[c1] - mu1 * scy;
  int stride = gridDim.x * 256;
  for (int idx = t; idx < total; idx += stride) {
    float2 h = ((const float2*)raw)[idx];
    float hx = fmaxf(fmaf(h.x, scx, shx), 0.f);
    float hy = fmaxf(fmaf(h.y, scy, shy), 0.f);
    ((uint_t*)hbn)[idx] = pack2(hx, hy);
  }
}

// ---------- aggregate (gather) ----------
// One wave per node, 10000 blocks (full gather concurrency, R8/R9-proven).
// Writes zin as hi/lo bf16 pair: uint2{hi2,lo2} per lane -> 512B/row, laid
// ONTO raw's bytes (raw fully consumed by bnrelu before this launch).
__global__ __launch_bounds__(256) void aggregate_k(
    const ushort_t* __restrict__ hbn, const ushort_t* __restrict__ comb,
    const uint32_t* __restrict__ sorted, const int* __restrict__ rs,
    const float* __restrict__ eps, int layer, uint2* zinout, int N)
{
  int wave = threadIdx.x >> 6, lane = threadIdx.x & 63;
  int n = blockIdx.x * 4 + wave;
  if (n >= N) return;
  int beg = rs[n], end = rs[n + 1];
  const uint_t* hb = (const uint_t*)hbn;
  const uint_t* cb = ((const uint_t*)comb) + (size_t)layer * 4096 * 64;
  float ax = 0.f, ay = 0.f;
  int i = beg;
  for (; i + 16 <= end; i += 16) {
    uint32_t p[16];
#pragma unroll
    for (int j = 0; j < 16; ++j) p[j] = sorted[i + j];
    uint_t hv[16], ee[16];
#pragma unroll
    for (int j = 0; j < 16; ++j) {
      hv[j] = hb[(size_t)(p[j] & 0xFFFFu) * 64 + lane];
      ee[j] = cb[(p[j] >> 16) * 64 + lane];
    }
#pragma unroll
    for (int j = 0; j < 16; ++j) {
      ax += fmaxf(bf2f(hv[j]) + bf2f(ee[j]), 0.f);
      ay += fmaxf(bf2f(hv[j] >> 16) + bf2f(ee[j] >> 16), 0.f);
    }
  }
  for (; i + 4 <= end; i += 4) {
    uint32_t p[4];
#pragma unroll
    for (int j = 0; j < 4; ++j) p[j] = sorted[i + j];
    uint_t hv[4], ee[4];
#pragma unroll
    for (int j = 0; j < 4; ++j) {
      hv[j] = hb[(size_t)(p[j] & 0xFFFFu) * 64 + lane];
      ee[j] = cb[(p[j] >> 16) * 64 + lane];
    }
#pragma unroll
    for (int j = 0; j < 4; ++j) {
      ax += fmaxf(bf2f(hv[j]) + bf2f(ee[j]), 0.f);
      ay += fmaxf(bf2f(hv[j] >> 16) + bf2f(ee[j] >> 16), 0.f);
    }
  }
  for (; i < end; ++i) {
    uint32_t p = sorted[i];
    uint_t ee = cb[(p >> 16) * 64 + lane];
    uint_t hv = hb[(size_t)(p & 0xFFFFu) * 64 + lane];
    ax += fmaxf(bf2f(hv) + bf2f(ee), 0.f);
    ay += fmaxf(bf2f(hv >> 16) + bf2f(ee >> 16), 0.f);
  }
  float s = 1.f + eps[layer];
  uint_t hn = hb[(size_t)n * 64 + lane];
  float zx = fmaf(s, bf2f(hn), ax);
  float zy = fmaf(s, bf2f(hn >> 16), ay);
  ushort_t hxz = f2bf(zx), hyz = f2bf(zy);
  float lox = zx - bf2f(hxz), loy = zy - bf2f(hyz);
  uint2 o;
  o.x = (uint_t)hxz | ((uint_t)hyz << 16);
  o.y = pack2(lox, loy);
  zinout[(size_t)n * 64 + lane] = o;
}

// ---------- GEMM1 ----------
// 512 threads = 8 waves; block owns 64 rows. Stage zin hi/lo from global into
// XOR-swizzled LDS (As=hi, Al=lo) -> hi/lo GEMM1 [64,128]@[128,256] -> z1 =
// acc+b1 as bf16 written to the SAME bytes (zin/z1 alias; block-matched:
// all reads complete before barrier, writes after). BN1 stats atomics.
// Block 0 zeroes BN2 stats region (stats[512..767]).
__global__ __launch_bounds__(512, 4) void gemm1_k(
    const uint2* zin, const ushort_t* __restrict__ bswz,
    const float* __restrict__ bias, ushort_t* z1bf,
    float* __restrict__ stats)
{
  __shared__ ushort_t As[64 * 128];   // hi, 16 KB
  __shared__ ushort_t Al[64 * 128];   // lo, 16 KB
  int tid = threadIdx.x;
  int wave = tid >> 6, lane = tid & 63;
  int row0 = blockIdx.x * 64;
  if (blockIdx.x == 0 && tid < 256) stats[512 + tid] = 0.f;
  {
    const uint2* src = zin + (size_t)row0 * 64;
#pragma unroll
    for (int i = 0; i < 8; ++i) {
      int idx = tid + 512 * i;        // 4096 = 64 rows x 64 lanes
      int r = idx >> 6, l = idx & 63, c = 2 * l;
      uint2 v = src[idx];
      int scol = (((c >> 3) ^ (r & 15)) << 3) | (c & 7);
      *(uint_t*)&As[r * 128 + scol] = v.x;
      *(uint_t*)&Al[r * 128 + scol] = v.y;
    }
  }
  __syncthreads();
  int lr = lane & 31, half = lane >> 5;
  int nt = wave;
  f32x16 acc0 = zero16(), acc1 = zero16();
  const bf16x8* Bp = (const bf16x8*)bswz;
#pragma unroll
  for (int s = 0; s < 8; ++s) {
    int k = s * 16 + half * 8;
    int scol = ((k >> 3) ^ (lr & 15)) << 3;
    bf16x8 b = Bp[(s * 8 + nt) * 64 + lane];
    bf16x8 ah0 = *(const bf16x8*)&As[lr * 128 + scol];
    bf16x8 al0 = *(const bf16x8*)&Al[lr * 128 + scol];
    bf16x8 ah1 = *(const bf16x8*)&As[(32 + lr) * 128 + scol];
    bf16x8 al1 = *(const bf16x8*)&Al[(32 + lr) * 128 + scol];
    acc0 = MFMA32(ah0, b, acc0);
    acc0 = MFMA32(al0, b, acc0);
    acc1 = MFMA32(ah1, b, acc1);
    acc1 = MFMA32(al1, b, acc1);
  }
  int col = nt * 32 + lr;
  float bv = bias[col];
  float s0 = 0.f, q0 = 0.f;
#pragma unroll
  for (int r2 = 0; r2 < 16; ++r2) {
    int rrow = (r2 & 3) + 8 * (r2 >> 2) + 4 * half;
    float v0 = acc0[r2] + bv;
    float v1 = acc1[r2] + bv;
    z1bf[(size_t)(row0 + rrow) * 256 + col] = f2bf(v0);
    z1bf[(size_t)(row0 + 32 + rrow) * 256 + col] = f2bf(v1);
    s0 += v0 + v1;
    q0 += v0 * v0 + v1 * v1;
  }
  s0 += __shfl_xor(s0, 32);
  q0 += __shfl_xor(q0, 32);
  if (lane < 32) {
    atomicAdd(&stats[col], s0);
    atomicAdd(&stats[256 + col], q0);
  }
}

// ---------- GEMM2 ----------
// rawz is BOTH the z1 bf16 source and the fp32 z2 destination (byte-aliased,
// block-matched). BN1+relu applied during staging (single post-BN1 bf16
// rounding), GEMM2 [64,256]@[256,128]+b2 -> raw fp32, accumulate BN2 stats.
__global__ __launch_bounds__(256) void mlp2_k(
    float* rawz, const float* __restrict__ stats1,
    const float* __restrict__ g1, const float* __restrict__ bb1,
    const ushort_t* __restrict__ bswz2, const float* __restrict__ b2,
    float* __restrict__ stats2, float invN)
{
  __shared__ ushort_t Bs[64 * 256];   // 32 KB
  __shared__ float sc1[256], sh1[256];
  int tid = threadIdx.x;
  int wave = tid >> 6, lane = tid & 63;
  int lr = lane & 31, half = lane >> 5;
  int row0 = blockIdx.x * 64;
  {
    float mu = stats1[tid] * invN;
    float var = stats1[256 + tid] * invN - mu * mu;
    float r = rsqrtf(var + 1e-5f) * g1[tid];
    sc1[tid] = r;
    sh1[tid] = bb1[tid] - mu * r;
  }
  __syncthreads();
  {
    const uint4* src = (const uint4*)((const ushort_t*)rawz + (size_t)row0 * 256);
#pragma unroll
    for (int i = 0; i < 8; ++i) {
      int idx = tid + 256 * i;        // 2048 chunks of 8 bf16
      int r = idx >> 5, c = (idx & 31) * 8;
      uint4 v = src[idx];
      float f0 = fmaxf(fmaf(bf2f(v.x), sc1[c], sh1[c]), 0.f);
      float f1 = fmaxf(fmaf(bf2f(v.x >> 16), sc1[c + 1], sh1[c + 1]), 0.f);
      float f2 = fmaxf(fmaf(bf2f(v.y), sc1[c + 2], sh1[c + 2]), 0.f);
      float f3 = fmaxf(fmaf(bf2f(v.y >> 16), sc1[c + 3], sh1[c + 3]), 0.f);
      float f4 = fmaxf(fmaf(bf2f(v.z), sc1[c + 4], sh1[c + 4]), 0.f);
      float f5 = fmaxf(fmaf(bf2f(v.z >> 16), sc1[c + 5], sh1[c + 5]), 0.f);
      float f6 = fmaxf(fmaf(bf2f(v.w), sc1[c + 6], sh1[c + 6]), 0.f);
      float f7 = fmaxf(fmaf(bf2f(v.w >> 16), sc1[c + 7], sh1[c + 7]), 0.f);
      uint4 o;
      o.x = pack2(f0, f1);
      o.y = pack2(f2, f3);
      o.z = pack2(f4, f5);
      o.w = pack2(f6, f7);
      int scol = ((c >> 3) ^ (r & 15)) << 3;
      *(uint4*)&Bs[r * 256 + scol] = o;
    }
  }
  __syncthreads();
  f32x16 acc0 = zero16(), acc1 = zero16();
  {
    const bf16x8* Bp2 = (const bf16x8*)bswz2;
#pragma unroll
    for (int s = 0; s < 16; ++s) {
      int k = s * 16 + half * 8;
      int scol = ((k >> 3) ^ (lr & 15)) << 3;
      bf16x8 a0 = *(const bf16x8*)&Bs[lr * 256 + scol];
      bf16x8 a1 = *(const bf16x8*)&Bs[(32 + lr) * 256 + scol];
      bf16x8 b = Bp2[(s * 4 + wave) * 64 + lane];
      acc0 = MFMA32(a0, b, acc0);
      acc1 = MFMA32(a1, b, acc1);
    }
  }
  int col = wave * 32 + lr;
  float bv = b2[col];
  float s0 = 0.f, q0 = 0.f;
  auto emit = [&](const f32x16& a, int mtb) {
#pragma unroll
    for (int r2 = 0; r2 < 16; ++r2) {
      int row = row0 + mtb + (r2 & 3) + 8 * (r2 >> 2) + 4 * half;
      float v = a[r2] + bv;
      rawz[(size_t)row * 128 + col] = v;
      s0 += v;
      q0 += v * v;
    }
  };
  emit(acc0, 0);
  emit(acc1, 32);
  s0 += __shfl_xor(s0, 32);
  q0 += __shfl_xor(q0, 32);
  if (lane < 32) {
    atomicAdd(&stats2[col], s0);
    atomicAdd(&stats2[128 + col], q0);
  }
}

// Final projection: BN(stats2) on fp32 raw at load (no relu), then
// [64,128]@[128,256]+linb -> fp32 out.
__global__ __launch_bounds__(256) void final_proj_k(
    const float* __restrict__ inf, const ushort_t* __restrict__ bswz,
    const float* __restrict__ bias, const float* __restrict__ stats2,
    const float* __restrict__ g, const float* __restrict__ bb,
    float* __restrict__ outf, float invN)
{
  __shared__ ushort_t As[64 * 128];
  __shared__ float sc[128], sh[128];
  int tid = threadIdx.x;
  int wave = tid >> 6, lane = tid & 63;
  int lr = lane & 31, half = lane >> 5;
  int row0 = blockIdx.x * 64;
  if (tid < 128) {
    int c = tid;
    float mu = stats2[c] * invN;
    float var = stats2[128 + c] * invN - mu * mu;
    float r = rsqrtf(var + 1e-5f) * g[c];
    sc[c] = r;
    sh[c] = bb[c] - mu * r;
  }
  __syncthreads();
  {
    const float4* src = (const float4*)(inf + (size_t)row0 * 128);
#pragma unroll
    for (int i = 0; i < 8; ++i) {
      int idx = tid + 256 * i;
      int r = idx >> 5, c = (idx & 31) * 4;
      float4 v = src[idx];
      v.x = fmaf(v.x, sc[c], sh[c]);
      v.y = fmaf(v.y, sc[c + 1], sh[c + 1]);
      v.z = fmaf(v.z, sc[c + 2], sh[c + 2]);
      v.w = fmaf(v.w, sc[c + 3], sh[c + 3]);
      uint2 o;
      o.x = pack2(v.x, v.y);
      o.y = pack2(v.z, v.w);
      int scol = (((c >> 3) ^ (r & 15)) << 3) | (c & 7);
      *(uint2*)&As[r * 128 + scol] = o;
    }
  }
  __syncthreads();
  int nt0 = wave * 2, nt1 = nt0 + 1;
  f32x16 acc00 = zero16(), acc01 = zero16(), acc10 = zero16(), acc11 = zero16();
  const bf16x8* Bp = (const bf16x8*)bswz;
#pragma unroll
  for (int s = 0; s < 8; ++s) {
    int k = s * 16 + half * 8;
    int scol = ((k >> 3) ^ (lr & 15)) << 3;
    bf16x8 a0 = *(const bf16x8*)&As[lr * 128 + scol];
    bf16x8 a1 = *(const bf16x8*)&As[(32 + lr) * 128 + scol];
    bf16x8 b0 = Bp[(s * 8 + nt0) * 64 + lane];
    bf16x8 b1 = Bp[(s * 8 + nt1) * 64 + lane];
    acc00 = MFMA32(a0, b0, acc00);
    acc10 = MFMA32(a1, b0, acc10);
    acc01 = MFMA32(a0, b1, acc01);
    acc11 = MFMA32(a1, b1, acc11);
  }
  int col0 = nt0 * 32 + lr, col1 = nt1 * 32 + lr;
  float bv0 = bias[col0], bv1 = bias[col1];
  auto emit = [&](const f32x16& a, int mtb, int col, float bv) {
#pragma unroll
    for (int r2 = 0; r2 < 16; ++r2) {
      int row = row0 + mtb + (r2 & 3) + 8 * (r2 >> 2) + 4 * half;
      outf[(size_t)row * 256 + col] = a[r2] + bv;
    }
  };
  emit(acc00, 0, col0, bv0);
  emit(acc10, 32, col0, bv0);
  emit(acc01, 0, col1, bv1);
  emit(acc11, 32, col1, bv1);
}

extern "C" void kernel_launch(void* const* d_in, const int* in_sizes, int n_in,
                              void* d_out, int out_size, void* d_ws, size_t ws_size,
                              hipStream_t stream)
{
  const int* x = (const int*)d_in[0];
  const int* ei = (const int*)d_in[1];
  const int* ea = (const int*)d_in[2];
  const float* aemb = (const float*)d_in[3];
  const float* bemb = (const float*)d_in[4];
  const float* eps = (const float*)d_in[5];
  const float* w1 = (const float*)d_in[6];
  const float* b1 = (const float*)d_in[7];
  const float* bn1g = (const float*)d_in[8];
  const float* bn1b = (const float*)d_in[9];
  const float* w2 = (const float*)d_in[10];
  const float* b2 = (const float*)d_in[11];
  const float* bng = (const float*)d_in[12];
  const float* bnb = (const float*)d_in[13];
  const float* linw = (const float*)d_in[14];
  const float* linb = (const float*)d_in[15];
  int N = in_sizes[0] / 9;   // 40000
  int E = in_sizes[1] / 2;   // 640000
  int nb = (N + 255) / 256;

  char* ws = (char*)d_ws;
  size_t off = 0;
  auto alloc = [&](size_t bytes) {
    void* p = ws + off;
    off += (bytes + 255) & ~(size_t)255;
    return p;
  };
  // raw time-shares: zin hi/lo (512B/row) -> z1 bf16 (512B/row) -> z2 fp32.
  float* raw = (float*)alloc((size_t)N * 128 * 4);          // 20.48 MB
  ushort_t* hbn = (ushort_t*)alloc((size_t)N * 128 * 2);    // 10.24 MB
  ushort_t* comb = (ushort_t*)alloc((size_t)5 * 4096 * 128 * 2);  // 5.24 MB
  ushort_t* bswz1 = (ushort_t*)alloc((size_t)6 * 32768 * 2);
  ushort_t* bswz2 = (ushort_t*)alloc((size_t)5 * 32768 * 2);
  uint32_t* sorted = (uint32_t*)alloc((size_t)E * 4);       // 2.56 MB
  int* rs = (int*)alloc((size_t)(N + 1) * 4);
  int* cursor = (int*)alloc((size_t)N * 4);
  int* cnt = (int*)alloc((size_t)N * 4);
  int* bsum = (int*)alloc((size_t)nb * 4);
  float* stats = (float*)alloc(768 * 4);  // [sum1:256][sq1:256][sum2:128][sq2:128]
  float invN = 1.f / (float)N;

  bond_comb_k<<<(5 * 4096 * 64 + 255) / 256, 256, 0, stream>>>(bemb, comb);
  swz_all_k<<<(11 * 4096 + 255) / 256, 256, 0, stream>>>(w1, linw, w2, bswz1, bswz2);

  atom_encode_k<<<(N * 64 + 255) / 256, 256, 0, stream>>>(x, aemb, hbn, stats, N);
  zero_int_k<<<(N + 255) / 256, 256, 0, stream>>>(cnt, N);
  hist_k<<<(E + 255) / 256, 256, 0, stream>>>(ei, cnt, E);
  block_sum_k<<<nb, 256, 0, stream>>>(cnt, bsum, N);
  scan_bsum_k<<<1, 256, 0, stream>>>(bsum, rs + N, nb);
  scan_write_k<<<nb, 256, 0, stream>>>(cnt, bsum, rs, cursor, N);
  scatter_k<<<(E + 255) / 256, 256, 0, stream>>>(ei, ea, cursor, sorted, E);

  for (int l = 0; l < 5; ++l) {
    if (l > 0) {
      bnrelu_k<<<2048, 256, 0, stream>>>(
          raw, stats + 512, bng + (size_t)(l - 1) * 128,
          bnb + (size_t)(l - 1) * 128, hbn, stats, invN, N * 64);
    }
    aggregate_k<<<(N + 3) / 4, 256, 0, stream>>>(
        hbn, comb, sorted, rs, eps, l, (uint2*)raw, N);
    gemm1_k<<<N / 64, 512, 0, stream>>>(
        (const uint2*)raw, bswz1 + (size_t)l * 32768, b1 + (size_t)l * 256,
        (ushort_t*)raw, stats);
    mlp2_k<<<N / 64, 256, 0, stream>>>(
        raw, stats, bn1g + (size_t)l * 256, bn1b + (size_t)l * 256,
        bswz2 + (size_t)l * 32768, b2 + (size_t)l * 128,
        stats + 512, invN);
  }
  final_proj_k<<<N / 64, 256, 0, stream>>>(
      raw, bswz1 + (size_t)5 * 32768, linb, stats + 512,
      bng + (size_t)4 * 128, bnb + (size_t)4 * 128, (float*)d_out, invN);
}

// Round 8
// 528.061 us; speedup vs baseline: 1.2030x; 1.2030x over previous
//
#include <hip/hip_runtime.h>
#include <stdint.h>

// GIN GNN: N=40000, E=640000, H=128, 5 layers, PROJ=256.
// R16: R15 + 8-way banked BN stats. Theory: gemm1/mlp2 pay a serialized
// device-scope atomic tail (625 blocks x 1 atomicAdd per column on 512/256
// shared addresses ~= 30us chains). stats is now [8][768]; producers add
// into bank blockIdx&7 (chain 625 -> ~78); consumers sum 8 banks in their
// prologue. Everything else identical to R15 (passed, 635us, absmax 0.094).

typedef unsigned short ushort_t;
typedef unsigned int uint_t;
typedef __attribute__((ext_vector_type(8))) short bf16x8;
typedef __attribute__((ext_vector_type(16))) float f32x16;

#define MFMA32(a, b, c) __builtin_amdgcn_mfma_f32_32x32x16_bf16(a, b, c, 0, 0, 0)
#define NBANK 8
#define BANKSZ 768   // [sum1:256][sq1:256][sum2:128][sq2:128]

__device__ inline ushort_t f2bf(float f) {
  uint_t u = __builtin_bit_cast(uint_t, f);
  u += 0x7FFFu + ((u >> 16) & 1u);
  return (ushort_t)(u >> 16);
}
__device__ inline float bf2f(uint_t h) {  // low 16 bits
  uint_t u = (h & 0xFFFFu) << 16;
  return __builtin_bit_cast(float, u);
}
__device__ inline uint_t pack2(float a, float b) {
  return (uint_t)f2bf(a) | ((uint_t)f2bf(b) << 16);
}
__device__ inline f32x16 zero16() {
  f32x16 z;
#pragma unroll
  for (int i = 0; i < 16; ++i) z[i] = 0.f;
  return z;
}

// ---------- precompute ----------

// comb[l][c][128] bf16, c = a0|a1<<4|a2<<8
__global__ __launch_bounds__(256) void bond_comb_k(
    const float* __restrict__ bemb, ushort_t* __restrict__ comb)
{
  int idx = blockIdx.x * 256 + threadIdx.x;  // over 5*4096*64
  if (idx >= 5 * 4096 * 64) return;
  int lane = idx & 63, c = (idx >> 6) & 4095, l = idx >> 18;
  const float2* b2 = (const float2*)(bemb + (size_t)l * 3 * 16 * 128);
  float2 e0 = b2[(c & 15) * 64 + lane];
  float2 e1 = b2[(16 + ((c >> 4) & 15)) * 64 + lane];
  float2 e2 = b2[(32 + (c >> 8)) * 64 + lane];
  ((uint_t*)comb)[idx] = pack2(e0.x + e1.x + e2.x, e0.y + e1.y + e2.y);
}

// All 11 weight swizzles in one launch. m<6: K=128,N=256 (w1 x5, linw);
// m>=6: K=256,N=128 (w2 x5).
__global__ __launch_bounds__(256) void swz_all_k(
    const float* __restrict__ w1, const float* __restrict__ linw,
    const float* __restrict__ w2, ushort_t* __restrict__ bswz1,
    ushort_t* __restrict__ bswz2)
{
  int t = blockIdx.x * 256 + threadIdx.x;  // 11*4096
  if (t >= 11 * 4096) return;
  int m = t >> 12, tt = t & 4095, lane = tt & 63;
  if (m < 6) {
    const float* w = (m < 5) ? (w1 + (size_t)m * 32768) : linw;
    ushort_t* o = bswz1 + (size_t)m * 32768;
    int nt = (tt >> 6) & 7, s = tt >> 9;
    int kb = s * 16 + (lane >> 5) * 8, n = nt * 32 + (lane & 31);
    ushort_t tmp[8];
#pragma unroll
    for (int j = 0; j < 8; ++j) tmp[j] = f2bf(w[(size_t)(kb + j) * 256 + n]);
    ((uint4*)o)[tt] = *(uint4*)tmp;
  } else {
    int mm = m - 6;
    const float* w = w2 + (size_t)mm * 32768;
    ushort_t* o = bswz2 + (size_t)mm * 32768;
    int nt = (tt >> 6) & 3, s = tt >> 8;
    int kb = s * 16 + (lane >> 5) * 8, n = nt * 32 + (lane & 31);
    ushort_t tmp[8];
#pragma unroll
    for (int j = 0; j < 8; ++j) tmp[j] = f2bf(w[(size_t)(kb + j) * 128 + n]);
    ((uint4*)o)[tt] = *(uint4*)tmp;
  }
}

// ---------- graph preprocessing ----------

__global__ void zero_int_k(int* p, int n) {
  int i = blockIdx.x * 256 + threadIdx.x;
  if (i < n) p[i] = 0;
}

__global__ void hist_k(const int* __restrict__ ei, int* __restrict__ cnt, int E) {
  int e = blockIdx.x * 256 + threadIdx.x;
  if (e >= E) return;
  atomicAdd(&cnt[ei[E + e]], 1);
}

__global__ __launch_bounds__(256) void block_sum_k(
    const int* __restrict__ cnt, int* __restrict__ bsum, int N)
{
  __shared__ int red[256];
  int t = threadIdx.x, idx = blockIdx.x * 256 + t;
  red[t] = (idx < N) ? cnt[idx] : 0;
  __syncthreads();
  for (int o = 128; o > 0; o >>= 1) {
    if (t < o) red[t] += red[t + o];
    __syncthreads();
  }
  if (t == 0) bsum[blockIdx.x] = red[0];
}

__global__ __launch_bounds__(256) void scan_bsum_k(
    int* __restrict__ bsum, int* __restrict__ rsN, int nb)
{
  __shared__ int s[256];
  int t = threadIdx.x;
  s[t] = (t < nb) ? bsum[t] : 0;
  __syncthreads();
  for (int o = 1; o < 256; o <<= 1) {
    int v = (t >= o) ? s[t - o] : 0;
    __syncthreads();
    s[t] += v;
    __syncthreads();
  }
  if (t < nb) bsum[t] = (t == 0) ? 0 : s[t - 1];
  if (t == nb - 1) *rsN = s[t];
}

__global__ __launch_bounds__(256) void scan_write_k(
    const int* __restrict__ cnt, const int* __restrict__ bsum,
    int* __restrict__ rs, int* __restrict__ cursor, int N)
{
  __shared__ int s[256];
  int t = threadIdx.x, idx = blockIdx.x * 256 + t;
  int v = (idx < N) ? cnt[idx] : 0;
  s[t] = v;
  __syncthreads();
  for (int o = 1; o < 256; o <<= 1) {
    int u = (t >= o) ? s[t - o] : 0;
    __syncthreads();
    s[t] += u;
    __syncthreads();
  }
  int excl = s[t] - v + bsum[blockIdx.x];
  if (idx < N) { rs[idx] = excl; cursor[idx] = excl; }
}

__global__ void scatter_k(const int* __restrict__ ei, const int* __restrict__ ea,
                          int* __restrict__ cursor, uint32_t* __restrict__ sorted, int E)
{
  int e = blockIdx.x * 256 + threadIdx.x;
  if (e >= E) return;
  int src = ei[e], dst = ei[E + e];
  int a0 = ea[e * 3], a1 = ea[e * 3 + 1], a2 = ea[e * 3 + 2];
  int pos = atomicAdd(&cursor[dst], 1);
  sorted[pos] = (uint32_t)src | ((uint32_t)a0 << 16) | ((uint32_t)a1 << 20) | ((uint32_t)a2 << 24);
}

// ---------- node pipeline ----------

// Layer-0 h (no BN): write bf16 directly into hbn. Block 0 zeroes ALL stats
// banks (safe: no concurrent stats readers at this point).
__global__ __launch_bounds__(256) void atom_encode_k(
    const int* __restrict__ x, const float* __restrict__ aemb,
    ushort_t* __restrict__ hbn, float* __restrict__ stats, int N)
{
  if (blockIdx.x == 0) {
    for (int i = threadIdx.x; i < NBANK * BANKSZ; i += 256) stats[i] = 0.f;
  }
  int idx = blockIdx.x * 256 + threadIdx.x;
  if (idx >= N * 64) return;
  int n = idx >> 6, lane = idx & 63;
  const int* xr = x + n * 9;
  float sx = 0.f, sy = 0.f;
#pragma unroll
  for (int f = 0; f < 9; ++f) {
    float2 e = ((const float2*)(aemb + (size_t)(f * 128 + xr[f]) * 128))[lane];
    sx += e.x; sy += e.y;
  }
  ((uint_t*)hbn)[idx] = pack2(sx, sy);
}

// Materialize hbn = relu(BN(raw fp32)) as bf16, once per layer (layers 1..4).
// BN2 params from the 8 stats2 banks. Block 0 zeroes ONLY the stats1 regions
// of all banks (stats2 regions are concurrently read by other blocks).
__global__ __launch_bounds__(256) void bnrelu_k(
    const float* __restrict__ raw, float* __restrict__ stats,
    const float* __restrict__ g, const float* __restrict__ bb,
    ushort_t* __restrict__ hbn, float invN, int total)
{
  if (blockIdx.x == 0) {
    for (int i = threadIdx.x; i < NBANK * 512; i += 256) {
      int b = i >> 9, c = i & 511;
      stats[b * BANKSZ + c] = 0.f;
    }
  }
  int t = blockIdx.x * 256 + threadIdx.x;
  int lane = t & 63;
  int c0 = 2 * lane, c1 = c0 + 1;
  float s0 = 0.f, q0 = 0.f, s1 = 0.f, q1 = 0.f;
#pragma unroll
  for (int b = 0; b < NBANK; ++b) {
    const float* bk = stats + b * BANKSZ + 512;
    s0 += bk[c0]; q0 += bk[128 + c0];
    s1 += bk[c1]; q1 += bk[128 + c1];
  }
  float mu0 = s0 * invN, mu1 = s1 * invN;
  float v0 = q0 * invN - mu0 * mu0;
  float v1 = q1 * invN - mu1 * mu1;
  float scx = rsqrtf(v0 + 1e-5f) * g[c0];
  float scy = rsqrtf(v1 + 1e-5f) * g[c1];
  float shx = bb[c0] - mu0 * scx;
  float shy = bb[c1] - mu1 * scy;
  int stride = gridDim.x * 256;
  for (int idx = t; idx < total; idx += stride) {
    float2 h = ((const float2*)raw)[idx];
    float hx = fmaxf(fmaf(h.x, scx, shx), 0.f);
    float hy = fmaxf(fmaf(h.y, scy, shy), 0.f);
    ((uint_t*)hbn)[idx] = pack2(hx, hy);
  }
}

// ---------- aggregate (gather) ----------
// One wave per node, 10000 blocks (full gather concurrency).
// Writes zin as hi/lo bf16 pair: uint2{hi2,lo2} per lane -> 512B/row, laid
// ONTO raw's bytes (raw fully consumed by bnrelu before this launch).
__global__ __launch_bounds__(256) void aggregate_k(
    const ushort_t* __restrict__ hbn, const ushort_t* __restrict__ comb,
    const uint32_t* __restrict__ sorted, const int* __restrict__ rs,
    const float* __restrict__ eps, int layer, uint2* zinout, int N)
{
  int wave = threadIdx.x >> 6, lane = threadIdx.x & 63;
  int n = blockIdx.x * 4 + wave;
  if (n >= N) return;
  int beg = rs[n], end = rs[n + 1];
  const uint_t* hb = (const uint_t*)hbn;
  const uint_t* cb = ((const uint_t*)comb) + (size_t)layer * 4096 * 64;
  float ax = 0.f, ay = 0.f;
  int i = beg;
  for (; i + 16 <= end; i += 16) {
    uint32_t p[16];
#pragma unroll
    for (int j = 0; j < 16; ++j) p[j] = sorted[i + j];
    uint_t hv[16], ee[16];
#pragma unroll
    for (int j = 0; j < 16; ++j) {
      hv[j] = hb[(size_t)(p[j] & 0xFFFFu) * 64 + lane];
      ee[j] = cb[(p[j] >> 16) * 64 + lane];
    }
#pragma unroll
    for (int j = 0; j < 16; ++j) {
      ax += fmaxf(bf2f(hv[j]) + bf2f(ee[j]), 0.f);
      ay += fmaxf(bf2f(hv[j] >> 16) + bf2f(ee[j] >> 16), 0.f);
    }
  }
  for (; i + 4 <= end; i += 4) {
    uint32_t p[4];
#pragma unroll
    for (int j = 0; j < 4; ++j) p[j] = sorted[i + j];
    uint_t hv[4], ee[4];
#pragma unroll
    for (int j = 0; j < 4; ++j) {
      hv[j] = hb[(size_t)(p[j] & 0xFFFFu) * 64 + lane];
      ee[j] = cb[(p[j] >> 16) * 64 + lane];
    }
#pragma unroll
    for (int j = 0; j < 4; ++j) {
      ax += fmaxf(bf2f(hv[j]) + bf2f(ee[j]), 0.f);
      ay += fmaxf(bf2f(hv[j] >> 16) + bf2f(ee[j] >> 16), 0.f);
    }
  }
  for (; i < end; ++i) {
    uint32_t p = sorted[i];
    uint_t ee = cb[(p >> 16) * 64 + lane];
    uint_t hv = hb[(size_t)(p & 0xFFFFu) * 64 + lane];
    ax += fmaxf(bf2f(hv) + bf2f(ee), 0.f);
    ay += fmaxf(bf2f(hv >> 16) + bf2f(ee >> 16), 0.f);
  }
  float s = 1.f + eps[layer];
  uint_t hn = hb[(size_t)n * 64 + lane];
  float zx = fmaf(s, bf2f(hn), ax);
  float zy = fmaf(s, bf2f(hn >> 16), ay);
  ushort_t hxz = f2bf(zx), hyz = f2bf(zy);
  float lox = zx - bf2f(hxz), loy = zy - bf2f(hyz);
  uint2 o;
  o.x = (uint_t)hxz | ((uint_t)hyz << 16);
  o.y = pack2(lox, loy);
  zinout[(size_t)n * 64 + lane] = o;
}

// ---------- GEMM1 ----------
// 512 threads = 8 waves; block owns 64 rows. Stage zin hi/lo from global into
// XOR-swizzled LDS (As=hi, Al=lo) -> hi/lo GEMM1 [64,128]@[128,256] -> z1 =
// acc+b1 as bf16 written to the SAME bytes (zin/z1 alias; block-matched).
// BN1 stats atomics into bank blockIdx&7. Block 0 zeroes the stats2 regions
// of all banks.
__global__ __launch_bounds__(512, 4) void gemm1_k(
    const uint2* zin, const ushort_t* __restrict__ bswz,
    const float* __restrict__ bias, ushort_t* z1bf,
    float* __restrict__ stats)
{
  __shared__ ushort_t As[64 * 128];   // hi, 16 KB
  __shared__ ushort_t Al[64 * 128];   // lo, 16 KB
  int tid = threadIdx.x;
  int wave = tid >> 6, lane = tid & 63;
  int row0 = blockIdx.x * 64;
  if (blockIdx.x == 0) {
    for (int i = tid; i < NBANK * 256; i += 512) {
      int b = i >> 8, c = i & 255;
      stats[b * BANKSZ + 512 + c] = 0.f;
    }
  }
  {
    const uint2* src = zin + (size_t)row0 * 64;
#pragma unroll
    for (int i = 0; i < 8; ++i) {
      int idx = tid + 512 * i;        // 4096 = 64 rows x 64 lanes
      int r = idx >> 6, l = idx & 63, c = 2 * l;
      uint2 v = src[idx];
      int scol = (((c >> 3) ^ (r & 15)) << 3) | (c & 7);
      *(uint_t*)&As[r * 128 + scol] = v.x;
      *(uint_t*)&Al[r * 128 + scol] = v.y;
    }
  }
  __syncthreads();
  int lr = lane & 31, half = lane >> 5;
  int nt = wave;
  f32x16 acc0 = zero16(), acc1 = zero16();
  const bf16x8* Bp = (const bf16x8*)bswz;
#pragma unroll
  for (int s = 0; s < 8; ++s) {
    int k = s * 16 + half * 8;
    int scol = ((k >> 3) ^ (lr & 15)) << 3;
    bf16x8 b = Bp[(s * 8 + nt) * 64 + lane];
    bf16x8 ah0 = *(const bf16x8*)&As[lr * 128 + scol];
    bf16x8 al0 = *(const bf16x8*)&Al[lr * 128 + scol];
    bf16x8 ah1 = *(const bf16x8*)&As[(32 + lr) * 128 + scol];
    bf16x8 al1 = *(const bf16x8*)&Al[(32 + lr) * 128 + scol];
    acc0 = MFMA32(ah0, b, acc0);
    acc0 = MFMA32(al0, b, acc0);
    acc1 = MFMA32(ah1, b, acc1);
    acc1 = MFMA32(al1, b, acc1);
  }
  int col = nt * 32 + lr;
  float bv = bias[col];
  float s0 = 0.f, q0 = 0.f;
#pragma unroll
  for (int r2 = 0; r2 < 16; ++r2) {
    int rrow = (r2 & 3) + 8 * (r2 >> 2) + 4 * half;
    float v0 = acc0[r2] + bv;
    float v1 = acc1[r2] + bv;
    z1bf[(size_t)(row0 + rrow) * 256 + col] = f2bf(v0);
    z1bf[(size_t)(row0 + 32 + rrow) * 256 + col] = f2bf(v1);
    s0 += v0 + v1;
    q0 += v0 * v0 + v1 * v1;
  }
  s0 += __shfl_xor(s0, 32);
  q0 += __shfl_xor(q0, 32);
  if (lane < 32) {
    float* bk = stats + (blockIdx.x & (NBANK - 1)) * BANKSZ;
    atomicAdd(&bk[col], s0);
    atomicAdd(&bk[256 + col], q0);
  }
}

// ---------- GEMM2 ----------
// rawz is BOTH the z1 bf16 source and the fp32 z2 destination (byte-aliased,
// block-matched). BN1 params summed from 8 banks; BN1+relu at staging (single
// post-BN1 bf16 rounding), GEMM2 [64,256]@[256,128]+b2 -> raw fp32, BN2
// stats atomics into bank blockIdx&7.
__global__ __launch_bounds__(256) void mlp2_k(
    float* rawz, float* __restrict__ stats,
    const float* __restrict__ g1, const float* __restrict__ bb1,
    const ushort_t* __restrict__ bswz2, const float* __restrict__ b2,
    float invN)
{
  __shared__ ushort_t Bs[64 * 256];   // 32 KB
  __shared__ float sc1[256], sh1[256];
  int tid = threadIdx.x;
  int wave = tid >> 6, lane = tid & 63;
  int lr = lane & 31, half = lane >> 5;
  int row0 = blockIdx.x * 64;
  {
    float s = 0.f, q = 0.f;
#pragma unroll
    for (int b = 0; b < NBANK; ++b) {
      const float* bk = stats + b * BANKSZ;
      s += bk[tid];
      q += bk[256 + tid];
    }
    float mu = s * invN;
    float var = q * invN - mu * mu;
    float r = rsqrtf(var + 1e-5f) * g1[tid];
    sc1[tid] = r;
    sh1[tid] = bb1[tid] - mu * r;
  }
  __syncthreads();
  {
    const uint4* src = (const uint4*)((const ushort_t*)rawz + (size_t)row0 * 256);
#pragma unroll
    for (int i = 0; i < 8; ++i) {
      int idx = tid + 256 * i;        // 2048 chunks of 8 bf16
      int r = idx >> 5, c = (idx & 31) * 8;
      uint4 v = src[idx];
      float f0 = fmaxf(fmaf(bf2f(v.x), sc1[c], sh1[c]), 0.f);
      float f1 = fmaxf(fmaf(bf2f(v.x >> 16), sc1[c + 1], sh1[c + 1]), 0.f);
      float f2 = fmaxf(fmaf(bf2f(v.y), sc1[c + 2], sh1[c + 2]), 0.f);
      float f3 = fmaxf(fmaf(bf2f(v.y >> 16), sc1[c + 3], sh1[c + 3]), 0.f);
      float f4 = fmaxf(fmaf(bf2f(v.z), sc1[c + 4], sh1[c + 4]), 0.f);
      float f5 = fmaxf(fmaf(bf2f(v.z >> 16), sc1[c + 5], sh1[c + 5]), 0.f);
      float f6 = fmaxf(fmaf(bf2f(v.w), sc1[c + 6], sh1[c + 6]), 0.f);
      float f7 = fmaxf(fmaf(bf2f(v.w >> 16), sc1[c + 7], sh1[c + 7]), 0.f);
      uint4 o;
      o.x = pack2(f0, f1);
      o.y = pack2(f2, f3);
      o.z = pack2(f4, f5);
      o.w = pack2(f6, f7);
      int scol = ((c >> 3) ^ (r & 15)) << 3;
      *(uint4*)&Bs[r * 256 + scol] = o;
    }
  }
  __syncthreads();
  f32x16 acc0 = zero16(), acc1 = zero16();
  {
    const bf16x8* Bp2 = (const bf16x8*)bswz2;
#pragma unroll
    for (int s = 0; s < 16; ++s) {
      int k = s * 16 + half * 8;
      int scol = ((k >> 3) ^ (lr & 15)) << 3;
      bf16x8 a0 = *(const bf16x8*)&Bs[lr * 256 + scol];
      bf16x8 a1 = *(const bf16x8*)&Bs[(32 + lr) * 256 + scol];
      bf16x8 b = Bp2[(s * 4 + wave) * 64 + lane];
      acc0 = MFMA32(a0, b, acc0);
      acc1 = MFMA32(a1, b, acc1);
    }
  }
  int col = wave * 32 + lr;
  float bv = b2[col];
  float s0 = 0.f, q0 = 0.f;
  auto emit = [&](const f32x16& a, int mtb) {
#pragma unroll
    for (int r2 = 0; r2 < 16; ++r2) {
      int row = row0 + mtb + (r2 & 3) + 8 * (r2 >> 2) + 4 * half;
      float v = a[r2] + bv;
      rawz[(size_t)row * 128 + col] = v;
      s0 += v;
      q0 += v * v;
    }
  };
  emit(acc0, 0);
  emit(acc1, 32);
  s0 += __shfl_xor(s0, 32);
  q0 += __shfl_xor(q0, 32);
  if (lane < 32) {
    float* bk = stats + (blockIdx.x & (NBANK - 1)) * BANKSZ + 512;
    atomicAdd(&bk[col], s0);
    atomicAdd(&bk[128 + col], q0);
  }
}

// Final projection: BN (8-bank stats2) on fp32 raw at load (no relu), then
// [64,128]@[128,256]+linb -> fp32 out.
__global__ __launch_bounds__(256) void final_proj_k(
    const float* __restrict__ inf, const ushort_t* __restrict__ bswz,
    const float* __restrict__ bias, const float* __restrict__ stats,
    const float* __restrict__ g, const float* __restrict__ bb,
    float* __restrict__ outf, float invN)
{
  __shared__ ushort_t As[64 * 128];
  __shared__ float sc[128], sh[128];
  int tid = threadIdx.x;
  int wave = tid >> 6, lane = tid & 63;
  int lr = lane & 31, half = lane >> 5;
  int row0 = blockIdx.x * 64;
  if (tid < 128) {
    int c = tid;
    float s = 0.f, q = 0.f;
#pragma unroll
    for (int b = 0; b < NBANK; ++b) {
      const float* bk = stats + b * BANKSZ + 512;
      s += bk[c];
      q += bk[128 + c];
    }
    float mu = s * invN;
    float var = q * invN - mu * mu;
    float r = rsqrtf(var + 1e-5f) * g[c];
    sc[c] = r;
    sh[c] = bb[c] - mu * r;
  }
  __syncthreads();
  {
    const float4* src = (const float4*)(inf + (size_t)row0 * 128);
#pragma unroll
    for (int i = 0; i < 8; ++i) {
      int idx = tid + 256 * i;
      int r = idx >> 5, c = (idx & 31) * 4;
      float4 v = src[idx];
      v.x = fmaf(v.x, sc[c], sh[c]);
      v.y = fmaf(v.y, sc[c + 1], sh[c + 1]);
      v.z = fmaf(v.z, sc[c + 2], sh[c + 2]);
      v.w = fmaf(v.w, sc[c + 3], sh[c + 3]);
      uint2 o;
      o.x = pack2(v.x, v.y);
      o.y = pack2(v.z, v.w);
      int scol = (((c >> 3) ^ (r & 15)) << 3) | (c & 7);
      *(uint2*)&As[r * 128 + scol] = o;
    }
  }
  __syncthreads();
  int nt0 = wave * 2, nt1 = nt0 + 1;
  f32x16 acc00 = zero16(), acc01 = zero16(), acc10 = zero16(), acc11 = zero16();
  const bf16x8* Bp = (const bf16x8*)bswz;
#pragma unroll
  for (int s = 0; s < 8; ++s) {
    int k = s * 16 + half * 8;
    int scol = ((k >> 3) ^ (lr & 15)) << 3;
    bf16x8 a0 = *(const bf16x8*)&As[lr * 128 + scol];
    bf16x8 a1 = *(const bf16x8*)&As[(32 + lr) * 128 + scol];
    bf16x8 b0 = Bp[(s * 8 + nt0) * 64 + lane];
    bf16x8 b1 = Bp[(s * 8 + nt1) * 64 + lane];
    acc00 = MFMA32(a0, b0, acc00);
    acc10 = MFMA32(a1, b0, acc10);
    acc01 = MFMA32(a0, b1, acc01);
    acc11 = MFMA32(a1, b1, acc11);
  }
  int col0 = nt0 * 32 + lr, col1 = nt1 * 32 + lr;
  float bv0 = bias[col0], bv1 = bias[col1];
  auto emit = [&](const f32x16& a, int mtb, int col, float bv) {
#pragma unroll
    for (int r2 = 0; r2 < 16; ++r2) {
      int row = row0 + mtb + (r2 & 3) + 8 * (r2 >> 2) + 4 * half;
      outf[(size_t)row * 256 + col] = a[r2] + bv;
    }
  };
  emit(acc00, 0, col0, bv0);
  emit(acc10, 32, col0, bv0);
  emit(acc01, 0, col1, bv1);
  emit(acc11, 32, col1, bv1);
}

extern "C" void kernel_launch(void* const* d_in, const int* in_sizes, int n_in,
                              void* d_out, int out_size, void* d_ws, size_t ws_size,
                              hipStream_t stream)
{
  const int* x = (const int*)d_in[0];
  const int* ei = (const int*)d_in[1];
  const int* ea = (const int*)d_in[2];
  const float* aemb = (const float*)d_in[3];
  const float* bemb = (const float*)d_in[4];
  const float* eps = (const float*)d_in[5];
  const float* w1 = (const float*)d_in[6];
  const float* b1 = (const float*)d_in[7];
  const float* bn1g = (const float*)d_in[8];
  const float* bn1b = (const float*)d_in[9];
  const float* w2 = (const float*)d_in[10];
  const float* b2 = (const float*)d_in[11];
  const float* bng = (const float*)d_in[12];
  const float* bnb = (const float*)d_in[13];
  const float* linw = (const float*)d_in[14];
  const float* linb = (const float*)d_in[15];
  int N = in_sizes[0] / 9;   // 40000
  int E = in_sizes[1] / 2;   // 640000
  int nb = (N + 255) / 256;

  char* ws = (char*)d_ws;
  size_t off = 0;
  auto alloc = [&](size_t bytes) {
    void* p = ws + off;
    off += (bytes + 255) & ~(size_t)255;
    return p;
  };
  // raw time-shares: zin hi/lo (512B/row) -> z1 bf16 (512B/row) -> z2 fp32.
  float* raw = (float*)alloc((size_t)N * 128 * 4);          // 20.48 MB
  ushort_t* hbn = (ushort_t*)alloc((size_t)N * 128 * 2);    // 10.24 MB
  ushort_t* comb = (ushort_t*)alloc((size_t)5 * 4096 * 128 * 2);  // 5.24 MB
  ushort_t* bswz1 = (ushort_t*)alloc((size_t)6 * 32768 * 2);
  ushort_t* bswz2 = (ushort_t*)alloc((size_t)5 * 32768 * 2);
  uint32_t* sorted = (uint32_t*)alloc((size_t)E * 4);       // 2.56 MB
  int* rs = (int*)alloc((size_t)(N + 1) * 4);
  int* cursor = (int*)alloc((size_t)N * 4);
  int* cnt = (int*)alloc((size_t)N * 4);
  int* bsum = (int*)alloc((size_t)nb * 4);
  float* stats = (float*)alloc((size_t)NBANK * BANKSZ * 4);  // 24 KB, 8 banks
  float invN = 1.f / (float)N;

  bond_comb_k<<<(5 * 4096 * 64 + 255) / 256, 256, 0, stream>>>(bemb, comb);
  swz_all_k<<<(11 * 4096 + 255) / 256, 256, 0, stream>>>(w1, linw, w2, bswz1, bswz2);

  atom_encode_k<<<(N * 64 + 255) / 256, 256, 0, stream>>>(x, aemb, hbn, stats, N);
  zero_int_k<<<(N + 255) / 256, 256, 0, stream>>>(cnt, N);
  hist_k<<<(E + 255) / 256, 256, 0, stream>>>(ei, cnt, E);
  block_sum_k<<<nb, 256, 0, stream>>>(cnt, bsum, N);
  scan_bsum_k<<<1, 256, 0, stream>>>(bsum, rs + N, nb);
  scan_write_k<<<nb, 256, 0, stream>>>(cnt, bsum, rs, cursor, N);
  scatter_k<<<(E + 255) / 256, 256, 0, stream>>>(ei, ea, cursor, sorted, E);

  for (int l = 0; l < 5; ++l) {
    if (l > 0) {
      bnrelu_k<<<2048, 256, 0, stream>>>(
          raw, stats, bng + (size_t)(l - 1) * 128,
          bnb + (size_t)(l - 1) * 128, hbn, invN, N * 64);
    }
    aggregate_k<<<(N + 3) / 4, 256, 0, stream>>>(
        hbn, comb, sorted, rs, eps, l, (uint2*)raw, N);
    gemm1_k<<<N / 64, 512, 0, stream>>>(
        (const uint2*)raw, bswz1 + (size_t)l * 32768, b1 + (size_t)l * 256,
        (ushort_t*)raw, stats);
    mlp2_k<<<N / 64, 256, 0, stream>>>(
        raw, stats, bn1g + (size_t)l * 256, bn1b + (size_t)l * 256,
        bswz2 + (size_t)l * 32768, b2 + (size_t)l * 128,
        invN);
  }
  final_proj_k<<<N / 64, 256, 0, stream>>>(
      raw, bswz1 + (size_t)5 * 32768, linb, stats,
      bng + (size_t)4 * 128, bnb + (size_t)4 * 128, (float*)d_out, invN);
}